// Round 15
// baseline (2744.003 us; speedup 1.0000x reference)
//
#include <hip/hip_runtime.h>
#include <hip/hip_bf16.h>

#define NB 2048
#define NF 6144
#define ND 768
#define BM 256
#define BN 192
#define BK 64
#define SPLITK 2
#define KCH (NF / SPLITK)  // 3072 per block
#define NTIL (KCH / BK)    // 48 K-tiles per block

// LDS: A dbuf 2 x 32 KB (bf16) | B tri-buf 3 x 24 KB (bf16) = 136 KB
#define A_BYTES (BM * 128)
#define B_BYTES (BN * 128)
#define BBUF_OFF (2 * A_BYTES)
#define LDS_TOTAL (2 * A_BYTES + 3 * B_BYTES)  // 139264

typedef __attribute__((ext_vector_type(4))) __bf16 bf16x4;
typedef __attribute__((ext_vector_type(8))) __bf16 bf16x8;
typedef __attribute__((ext_vector_type(4))) float f32x4;

// THE proven layout (0 conflicts, rounds 2-14): 128B rows of 64 bf16,
// 16B-slot 3-bit swizzle slot = (k>>3) ^ fswz(row).
__device__ __forceinline__ int fswz(int r) { return ((r & 7) ^ ((r >> 2) & 7)) & 7; }
__device__ __forceinline__ char* lds_addr(char* base, int row, int k) {
  const int blk = ((k >> 3) ^ fswz(row)) & 7;
  return base + row * 128 + (blk << 4) + ((k & 7) << 1);
}

__device__ __forceinline__ void async_ld16(void* lds, const void* g) {
  __builtin_amdgcn_global_load_lds(
      (const __attribute__((address_space(1))) void*)g,
      (__attribute__((address_space(3))) void*)lds, 16, 0, 0);
}

#define SBAR0() __builtin_amdgcn_sched_barrier(0)
#define LGKM(N)                                              \
  do {                                                       \
    asm volatile("s_waitcnt lgkmcnt(" #N ")" ::: "memory");  \
    SBAR0();                                                 \
  } while (0)
#define VMW(N)                                               \
  do {                                                       \
    asm volatile("s_waitcnt vmcnt(" #N ")" ::: "memory");    \
    SBAR0();                                                 \
  } while (0)
#define BARRIER()                 \
  do {                            \
    __builtin_amdgcn_s_barrier(); \
    SBAR0();                      \
  } while (0)

// out[b,d] = sum_l bias[l,d]  (clears 0xAA poison deterministically)
__global__ __launch_bounds__(256) void bias_init_kernel(
    const float* __restrict__ bias, const int* __restrict__ lidx,
    float* __restrict__ out) {
  int n = lidx[0] + 1;
  int i = blockIdx.x * 256 + threadIdx.x;
  if (i >= NB * ND) return;
  int d = i % ND;
  float s = 0.f;
  for (int l = 0; l < n; ++l) s += bias[l * ND + d];
  out[i] = s;
}

// W[l][f][d] fp32 -> Wt[l][d][f] bf16 (verified R12-R14, ~43us)
__global__ __launch_bounds__(256) void wt_kernel(
    const float* __restrict__ W, unsigned short* __restrict__ wt) {
  __shared__ float t[64][65];
  const int l = blockIdx.z, f0 = blockIdx.x * 64, d0 = blockIdx.y * 64;
  const int tid = threadIdx.x;
  const int fr = tid >> 4;
  const int dc4 = (tid & 15) * 4;
  const float* src = W + ((size_t)l * NF + f0 + fr) * ND + d0 + dc4;
#pragma unroll
  for (int i = 0; i < 4; ++i) {
    float4 v = *(const float4*)(src + (size_t)16 * i * ND);
    t[fr + 16 * i][dc4 + 0] = v.x;
    t[fr + 16 * i][dc4 + 1] = v.y;
    t[fr + 16 * i][dc4 + 2] = v.z;
    t[fr + 16 * i][dc4 + 3] = v.w;
  }
  __syncthreads();
  const int dr = tid >> 4;
  const int fc4 = (tid & 15) * 4;
  unsigned short* dst = wt + ((size_t)l * ND + d0 + dr) * NF + f0 + fc4;
#pragma unroll
  for (int i = 0; i < 4; ++i) {
    bf16x4 h;
    h[0] = (__bf16)t[fc4 + 0][dr + 16 * i];
    h[1] = (__bf16)t[fc4 + 1][dr + 16 * i];
    h[2] = (__bf16)t[fc4 + 2][dr + 16 * i];
    h[3] = (__bf16)t[fc4 + 3][dr + 16 * i];
    *(bf16x4*)(dst + (size_t)16 * i * NF) = h;
  }
}

// ---------------- main GEMM: sandwich + 2-tile-deep VMEM pipeline ----------
// 256x192, 8 waves (4m x 2n), BK=64, split-K x2.
// A: fp32 reg-staged DOUBLE set (avs0/avs1): loads for tile t+2 issued in P1
//    of t, consumed by ASTORE in P3 of t+1 (~5 phases ~3k cyc -> HBM covered).
// B: bf16 W^T via global_load_lds, tri-buffer, issued P2 for t+2.
// Boundary: counted vmcnt(11) (= this tile's 8 av + 3 DMA issues) -> all
// older VMEM (incl. B(t)'s DMAs) retired; never drains to 0 mid-loop.
__global__ __launch_bounds__(512, 1) void gemm_sw(
    const float* __restrict__ acts, const unsigned short* __restrict__ wt,
    const int* __restrict__ lidx, float* __restrict__ out, int nwg) {
  extern __shared__ char cbuf[];  // LDS_TOTAL

  // by-fastest decode + XCD swizzle (R8: FETCH 1.27GB -> 405MB)
  const int chunk = nwg >> 3;  // 96
  const int swz = (blockIdx.x & 7) * chunk + (blockIdx.x >> 3);
  const int by = swz & 3;  // id = by + 4*(m + 8*(ks + 2*l))
  int rem = swz >> 2;
  const int m = rem & 7; rem >>= 3;
  const int ks = rem & 1; rem >>= 1;
  const int l = rem;
  if (l > lidx[0]) return;  // uniform exit before any barrier

  const int brow = m * BM;
  const int ncol = by * BN;
  const int k0 = ks * KCH;

  const int tid = threadIdx.x;
  const int lane = tid & 63;
  const int wid = tid >> 6;          // 8 waves: 4m x 2n
  const int wrow = (wid >> 1) * 64;  // 0,64,128,192
  const int wcol = (wid & 1) * 96;   // 0,96

  f32x4 acc[4][6];
#pragma unroll
  for (int i = 0; i < 4; ++i)
#pragma unroll
    for (int j = 0; j < 6; ++j) acc[i][j] = (f32x4){0.f, 0.f, 0.f, 0.f};

  // A reg-staging: thread -> (row = tid>>3 (+64 per p), 8 consecutive k)
  const int s_arow = tid >> 3;
  const int s_ak = (tid & 7) * 8;
  const float* Aptr =
      acts + (size_t)l * NB * NF + (size_t)(brow + s_arow) * NF + k0 + s_ak;
  float4 avs0[4][2], avs1[4][2];  // two named staging sets (rule #20)

  // B DMA (R13/R14-proven): wave w, instr j covers rows r0=8*(3w+j); lane ->
  // row r0+(lane>>3), slot lane&7; global k-block = slot ^ fswz(row).
  const unsigned short* bSrc[3];
  int bDst[3];
#pragma unroll
  for (int j = 0; j < 3; ++j) {
    const int r0 = 8 * (3 * wid + j);
    const int r = r0 + (lane >> 3);
    const int ksl = (lane & 7) ^ fswz(r);
    bSrc[j] = wt + ((size_t)l * ND + ncol + r) * NF + k0 + ksl * 8;
    bDst[j] = r0 * 128;
  }

  auto DMA_B = [&](int t) {
    char* b = cbuf + BBUF_OFF + (size_t)(t % 3) * B_BYTES;
#pragma unroll
    for (int j = 0; j < 3; ++j)
      async_ld16(b + bDst[j], bSrc[j] + (size_t)t * BK);
  };

#define ALOADS(S, kb)                                                       \
  do {                                                                      \
    _Pragma("unroll") for (int p = 0; p < 4; ++p) {                         \
      S[p][0] = *(const float4*)(Aptr + (size_t)(64 * p) * NF + (kb));      \
      S[p][1] = *(const float4*)(Aptr + (size_t)(64 * p) * NF + (kb) + 4);  \
    }                                                                       \
  } while (0)

#define ASTORE(dst, S)                                                      \
  do {                                                                      \
    _Pragma("unroll") for (int p = 0; p < 4; ++p) {                         \
      bf16x8 h;                                                             \
      h[0] = (__bf16)S[p][0].x; h[1] = (__bf16)S[p][0].y;                   \
      h[2] = (__bf16)S[p][0].z; h[3] = (__bf16)S[p][0].w;                   \
      h[4] = (__bf16)S[p][1].x; h[5] = (__bf16)S[p][1].y;                   \
      h[6] = (__bf16)S[p][1].z; h[7] = (__bf16)S[p][1].w;                   \
      *(bf16x8*)lds_addr((dst), s_arow + 64 * p, s_ak) = h;                 \
    }                                                                       \
  } while (0)

#define BF_READ(dst, P)                                                     \
  _Pragma("unroll") for (int ni = 0; ni < 2; ++ni)                          \
    _Pragma("unroll") for (int s = 0; s < 2; ++s)                           \
      dst[ni][s] = *(const bf16x8*)lds_addr(                                \
          rB, wcol + (2 * (P) + ni) * 16 + (lane & 15),                     \
          s * 32 + (lane >> 4) * 8);

#define MFMA16(bf, P)                                                       \
  __builtin_amdgcn_s_setprio(1);                                            \
  _Pragma("unroll") for (int s = 0; s < 2; ++s)                             \
    _Pragma("unroll") for (int mi = 0; mi < 4; ++mi)                        \
      _Pragma("unroll") for (int ni = 0; ni < 2; ++ni)                      \
        acc[mi][2 * (P) + ni] = __builtin_amdgcn_mfma_f32_16x16x32_bf16(    \
            aF[mi][s], bf[ni][s], acc[mi][2 * (P) + ni], 0, 0, 0);          \
  __builtin_amdgcn_s_setprio(0);                                            \
  SBAR0();

// One K-tile: SCUR holds A(t+1) (issued tile t-1), SNEXT receives A(t+2).
#define TILE(SCUR, SNEXT)                                                   \
  do {                                                                      \
    /* P1: aF + bF0 reads | issue A-globals(t+2) */                         \
    BF_READ(bFa, 0)                                                         \
    _Pragma("unroll") for (int mi = 0; mi < 4; ++mi)                        \
      _Pragma("unroll") for (int s = 0; s < 2; ++s)                         \
        aF[mi][s] = *(const bf16x8*)lds_addr(                               \
            rA, wrow + mi * 16 + (lane & 15), s * 32 + (lane >> 4) * 8);    \
    if (more2) ALOADS(SNEXT, (t + 2) * BK);                                 \
    BARRIER();                                                              \
    LGKM(0);                                                                \
    MFMA16(bFa, 0)                                                          \
    BARRIER();                                                              \
    /* P2: bF1 reads | issue B-DMA(t+2) */                                  \
    BF_READ(bFb, 1)                                                         \
    if (more2) DMA_B(t + 2);                                                \
    BARRIER();                                                              \
    LGKM(0);                                                                \
    MFMA16(bFb, 1)                                                          \
    BARRIER();                                                              \
    /* P3: bF2 reads | cvt+write A(t+1) from SCUR (loads ~5 phases old) */  \
    BF_READ(bFc, 2)                                                         \
    if (more1) ASTORE(wA, SCUR);                                            \
    BARRIER();                                                              \
    LGKM(0);                                                                \
    MFMA16(bFc, 2)                                                          \
    /* boundary: counted wait; the 11 newest (av+DMA for t+2) may fly */    \
    if (more2) { VMW(11); } else { VMW(0); }                                \
    BARRIER();                                                              \
  } while (0)

  // ---- prologue: A(0)->LDS buf0; A(1) in avs0; B(0),B(1) DMA'd ----
  ALOADS(avs0, 0);
  ASTORE(cbuf, avs0);  // reg-dep waits own loads (startup only)
  ALOADS(avs0, BK);    // A(1), consumed in P3 of t=0
  DMA_B(0);
  DMA_B(1);
  VMW(0);
  LGKM(0);
  BARRIER();

  for (int t = 0; t < NTIL; ++t) {
    char* rA = cbuf + (size_t)(t & 1) * A_BYTES;
    char* rB = cbuf + BBUF_OFF + (size_t)(t % 3) * B_BYTES;
    char* wA = cbuf + (size_t)((t + 1) & 1) * A_BYTES;
    const bool more1 = (t + 1 < NTIL);
    const bool more2 = (t + 2 < NTIL);
    bf16x8 aF[4][2], bFa[2][2], bFb[2][2], bFc[2][2];
    if ((t & 1) == 0) {
      TILE(avs0, avs1);
    } else {
      TILE(avs1, avs0);
    }
  }

#undef TILE
#undef BF_READ
#undef MFMA16
#undef ALOADS
#undef ASTORE

  // ---- epilogue: atomic accumulate (24 blocks collide: 12L x 2K) ----
  // C/D layout (m89-verified): col = lane&15, row = (lane>>4)*4 + j
  const int orow = brow + wrow + ((lane >> 4) << 2);
  const int ocol = ncol + wcol + (lane & 15);
#pragma unroll
  for (int mi = 0; mi < 4; ++mi)
#pragma unroll
    for (int ni = 0; ni < 6; ++ni)
#pragma unroll
      for (int j = 0; j < 4; ++j)
        atomicAdd(out + (size_t)(orow + mi * 16 + j) * ND + (ocol + ni * 16),
                  acc[mi][ni][j]);
}

// ---------------- fallback (ws too small): R8 fused kernel ----------------
#define F_BUF (A_BYTES + B_BYTES)
#define LGKM0F()                                           \
  do {                                                     \
    asm volatile("s_waitcnt lgkmcnt(0)" ::: "memory");     \
    SBAR0();                                               \
  } while (0)
__global__ __launch_bounds__(512, 2) void gemm_fused(
    const float* __restrict__ acts, const float* __restrict__ W,
    const int* __restrict__ lidx, float* __restrict__ out, int nwg) {
  extern __shared__ char cbuf[];
  const int chunk = nwg >> 3;
  const int swz = (blockIdx.x & 7) * chunk + (blockIdx.x >> 3);
  const int by = swz & 3;
  int rem = swz >> 2;
  const int m = rem & 7; rem >>= 3;
  const int ks = rem & 1; rem >>= 1;
  const int l = rem;
  if (l > lidx[0]) return;
  const int brow = m * BM, ncol = by * BN, k0 = ks * KCH;
  const int tid = threadIdx.x, lane = tid & 63, wid = tid >> 6;
  const int wrow = (wid >> 1) * 64, wcol = (wid & 1) * 96;
  f32x4 acc[4][6];
#pragma unroll
  for (int i = 0; i < 4; ++i)
#pragma unroll
    for (int j = 0; j < 6; ++j) acc[i][j] = (f32x4){0.f, 0.f, 0.f, 0.f};
  const int s_arow = tid >> 3, s_ak = (tid & 7) * 8;
  const bool bstage = tid < 384;
  const int s_bd = (tid % 48) * 4, s_bk = (tid / 48) * 8;
  const float* Aptr =
      acts + (size_t)l * NB * NF + (size_t)(brow + s_arow) * NF + k0 + s_ak;
  const float* Bptr =
      W + (size_t)l * NF * ND + (size_t)(k0 + s_bk) * ND + (ncol + s_bd);
  float4 av[4][2]; float4 bv[8];
  auto LOADS = [&](int kb) {
#pragma unroll
    for (int p = 0; p < 4; ++p) {
      av[p][0] = *(const float4*)(Aptr + (size_t)(64 * p) * NF + kb);
      av[p][1] = *(const float4*)(Aptr + (size_t)(64 * p) * NF + kb + 4);
    }
    if (bstage) {
#pragma unroll
      for (int j = 0; j < 8; ++j)
        bv[j] = *(const float4*)(Bptr + (size_t)(kb + j) * ND);
    }
  };
  auto STORE = [&](char* cA_, char* cB_) {
#pragma unroll
    for (int p = 0; p < 4; ++p) {
      bf16x8 h;
      h[0] = (__bf16)av[p][0].x; h[1] = (__bf16)av[p][0].y;
      h[2] = (__bf16)av[p][0].z; h[3] = (__bf16)av[p][0].w;
      h[4] = (__bf16)av[p][1].x; h[5] = (__bf16)av[p][1].y;
      h[6] = (__bf16)av[p][1].z; h[7] = (__bf16)av[p][1].w;
      *(bf16x8*)lds_addr(cA_, s_arow + 64 * p, s_ak) = h;
    }
    if (bstage) {
#pragma unroll
      for (int dd = 0; dd < 4; ++dd) {
        bf16x8 h;
#pragma unroll
        for (int j = 0; j < 8; ++j) h[j] = (__bf16)bv[j][dd];
        *(bf16x8*)lds_addr(cB_, s_bd + dd, s_bk) = h;
      }
    }
  };
  LOADS(0);
  STORE(cbuf, cbuf + A_BYTES);
  for (int t = 0; t < NTIL; ++t) {
    const int cur = t & 1;
    char* rA = cbuf + (size_t)cur * F_BUF;
    char* rB = rA + A_BYTES;
    char* wA = cbuf + (size_t)(cur ^ 1) * F_BUF;
    char* wB = wA + A_BYTES;
    LGKM0F();
    BARRIER();
    if (t + 1 < NTIL) LOADS((t + 1) * BK);
    SBAR0();
    bf16x8 aF[4][2];
#pragma unroll
    for (int mi = 0; mi < 4; ++mi)
#pragma unroll
      for (int s = 0; s < 2; ++s)
        aF[mi][s] = *(const bf16x8*)lds_addr(
            rA, wrow + mi * 16 + (lane & 15), s * 32 + (lane >> 4) * 8);
#pragma unroll
    for (int p = 0; p < 3; ++p) {
      bf16x8 bF[2][2];
#pragma unroll
      for (int ni = 0; ni < 2; ++ni)
#pragma unroll
        for (int s = 0; s < 2; ++s)
          bF[ni][s] = *(const bf16x8*)lds_addr(
              rB, wcol + (2 * p + ni) * 16 + (lane & 15),
              s * 32 + (lane >> 4) * 8);
      LGKM0F();
      __builtin_amdgcn_s_setprio(1);
#pragma unroll
      for (int s = 0; s < 2; ++s)
#pragma unroll
        for (int mi = 0; mi < 4; ++mi)
#pragma unroll
          for (int ni = 0; ni < 2; ++ni)
            acc[mi][2 * p + ni] = __builtin_amdgcn_mfma_f32_16x16x32_bf16(
                aF[mi][s], bF[ni][s], acc[mi][2 * p + ni], 0, 0, 0);
      __builtin_amdgcn_s_setprio(0);
      SBAR0();
    }
    if (t + 1 < NTIL) STORE(wA, wB);
  }
  const int orow = brow + wrow + ((lane >> 4) << 2);
  const int ocol = ncol + wcol + (lane & 15);
#pragma unroll
  for (int mi = 0; mi < 4; ++mi)
#pragma unroll
    for (int ni = 0; ni < 6; ++ni)
#pragma unroll
      for (int j = 0; j < 4; ++j)
        atomicAdd(out + (size_t)(orow + mi * 16 + j) * ND + (ocol + ni * 16),
                  acc[mi][ni][j]);
}

extern "C" void kernel_launch(void* const* d_in, const int* in_sizes, int n_in,
                              void* d_out, int out_size, void* d_ws, size_t ws_size,
                              hipStream_t stream) {
  const float* acts = (const float*)d_in[0];
  const float* W    = (const float*)d_in[1];
  const float* bias = (const float*)d_in[2];
  const int*   lidx = (const int*)d_in[3];
  float* out = (float*)d_out;

  const int L = in_sizes[0] / (NB * NF);               // 12
  const int nwg = (ND / BN) * (NB / BM) * SPLITK * L;  // 768 = 3 x 256 CUs
  const size_t wsNeed = (size_t)L * NF * ND * 2;       // 113 MB bf16 W^T

  bias_init_kernel<<<dim3((NB * ND + 255) / 256), 256, 0, stream>>>(bias, lidx, out);

  if (ws_size >= wsNeed) {
    unsigned short* wsB = (unsigned short*)d_ws;
    wt_kernel<<<dim3(NF / 64, ND / 64, L), 256, 0, stream>>>(W, wsB);
    hipFuncSetAttribute((const void*)gemm_sw,
                        hipFuncAttributeMaxDynamicSharedMemorySize, LDS_TOTAL);
    gemm_sw<<<dim3(nwg), 512, LDS_TOTAL, stream>>>(acts, wsB, lidx, out, nwg);
  } else {
    hipFuncSetAttribute((const void*)gemm_fused,
                        hipFuncAttributeMaxDynamicSharedMemorySize, 2 * F_BUF);
    gemm_fused<<<dim3(nwg), 512, 2 * F_BUF, stream>>>(acts, W, lidx, out, nwg);
  }
}

// Round 16
// 469.201 us; speedup vs baseline: 5.8482x; 5.8482x over previous
//
#include <hip/hip_runtime.h>
#include <hip/hip_bf16.h>

#define NB 2048
#define NF 6144
#define ND 768
#define BM 256
#define BN 192
#define BK 64
#define SPLITK 2
#define KCH (NF / SPLITK)  // 3072 per block
#define NTIL (KCH / BK)    // 48 K-tiles per block

// LDS: A 256 rows x 128 B = 32 KB; B 192 rows x 128 B = 24 KB; dbuf = 112 KB
#define ABYTES (BM * 128)
#define BBYTES (BN * 128)
#define BUFBYTES (ABYTES + BBYTES)

typedef __attribute__((ext_vector_type(8))) __bf16 bf16x8;
typedef __attribute__((ext_vector_type(4))) float f32x4;

// Proven layout (0 conflicts, rounds 2-14): 128B rows of 64 bf16,
// 16B-slot 3-bit swizzle slot = (k>>3) ^ (row&7) ^ ((row>>2)&7)
__device__ __forceinline__ char* lds_addr(char* base, int row, int k) {
  const int blk = ((k >> 3) ^ (row & 7) ^ ((row >> 2) & 7)) & 7;
  return base + row * 128 + (blk << 4) + ((k & 7) << 1);
}

#define SBAR0() __builtin_amdgcn_sched_barrier(0)
#define LGKM0()                                            \
  do {                                                     \
    asm volatile("s_waitcnt lgkmcnt(0)" ::: "memory");     \
    SBAR0();                                               \
  } while (0)

// out[b,d] = sum_l bias[l,d]  (clears 0xAA poison deterministically)
__global__ __launch_bounds__(256) void bias_init_kernel(
    const float* __restrict__ bias, const int* __restrict__ lidx,
    float* __restrict__ out) {
  int n = lidx[0] + 1;
  int i = blockIdx.x * 256 + threadIdx.x;
  if (i >= NB * ND) return;
  int d = i % ND;
  float s = 0.f;
  for (int l = 0; l < n; ++l) s += bias[l * ND + d];
  out[i] = s;
}

// R8 kernel (best measured total: 475 us). 256x192 tile, 8 waves (4m x 2n),
// BK=64, split-K x2, LDS double-buffer, ONE lgkm-only barrier per K-tile
// (global loads stay in flight across it), by-fastest XCD decode
// (FETCH 1.27GB -> 405MB), 3 setprio-wrapped MFMA phases per tile.
__global__ __launch_bounds__(512, 2) void gemm_kernel(
    const float* __restrict__ acts, const float* __restrict__ W,
    const int* __restrict__ lidx, float* __restrict__ out, int nwg) {
  extern __shared__ char cbuf[];  // 2 * BUFBYTES

  const int chunk = nwg >> 3;  // 96
  const int swz = (blockIdx.x & 7) * chunk + (blockIdx.x >> 3);
  const int by = swz & 3;  // id = by + 4*(m + 8*(ks + 2*l))
  int rem = swz >> 2;
  const int m = rem & 7; rem >>= 3;
  const int ks = rem & 1; rem >>= 1;
  const int l = rem;
  if (l > lidx[0]) return;  // uniform exit before any barrier

  const int brow = m * BM;
  const int ncol = by * BN;
  const int k0 = ks * KCH;

  const int tid = threadIdx.x;
  const int lane = tid & 63;
  const int wid = tid >> 6;          // 8 waves: 4m x 2n
  const int wrow = (wid >> 1) * 64;  // 0,64,128,192
  const int wcol = (wid & 1) * 96;   // 0,96

  f32x4 acc[4][6];
#pragma unroll
  for (int i = 0; i < 4; ++i)
#pragma unroll
    for (int j = 0; j < 6; ++j) acc[i][j] = (f32x4){0.f, 0.f, 0.f, 0.f};

  // A staging: thread -> (row = tid>>3 (+64 per pass p<4), 8 consecutive k)
  const int s_arow = tid >> 3;
  const int s_ak = (tid & 7) * 8;
  // B staging: threads 0..383: (4 consecutive d, 8 consecutive k)
  const bool bstage = tid < 384;
  const int s_bd = (tid % 48) * 4;
  const int s_bk = (tid / 48) * 8;

  const float* Aptr =
      acts + (size_t)l * NB * NF + (size_t)(brow + s_arow) * NF + k0 + s_ak;
  const float* Bptr =
      W + (size_t)l * NF * ND + (size_t)(k0 + s_bk) * ND + (ncol + s_bd);

  float4 av[4][2];  // A: 4 row-passes x 8 k (32 VGPR)
  float4 bv[8];     // B: 8 k-rows x 4 d   (32 VGPR, waves 0-5)

  auto LOADS = [&](int kb) {
#pragma unroll
    for (int p = 0; p < 4; ++p) {
      av[p][0] = *(const float4*)(Aptr + (size_t)(64 * p) * NF + kb);
      av[p][1] = *(const float4*)(Aptr + (size_t)(64 * p) * NF + kb + 4);
    }
    if (bstage) {
#pragma unroll
      for (int j = 0; j < 8; ++j)
        bv[j] = *(const float4*)(Bptr + (size_t)(kb + j) * ND);
    }
  };

  auto STORE = [&](char* cA_, char* cB_) {
#pragma unroll
    for (int p = 0; p < 4; ++p) {
      bf16x8 h;
      h[0] = (__bf16)av[p][0].x; h[1] = (__bf16)av[p][0].y;
      h[2] = (__bf16)av[p][0].z; h[3] = (__bf16)av[p][0].w;
      h[4] = (__bf16)av[p][1].x; h[5] = (__bf16)av[p][1].y;
      h[6] = (__bf16)av[p][1].z; h[7] = (__bf16)av[p][1].w;
      *(bf16x8*)lds_addr(cA_, s_arow + 64 * p, s_ak) = h;
    }
    if (bstage) {
#pragma unroll
      for (int dd = 0; dd < 4; ++dd) {
        bf16x8 h;
#pragma unroll
        for (int j = 0; j < 8; ++j) h[j] = (__bf16)bv[j][dd];
        *(bf16x8*)lds_addr(cB_, s_bd + dd, s_bk) = h;
      }
    }
  };

  // ---- prologue: tile 0 staged into buf0 (self-waiting, once) ----
  LOADS(0);
  STORE(cbuf, cbuf + ABYTES);

  for (int t = 0; t < NTIL; ++t) {
    const int cur = t & 1;
    char* rA = cbuf + (size_t)cur * BUFBYTES;
    char* rB = rA + ABYTES;
    char* wA = cbuf + (size_t)(cur ^ 1) * BUFBYTES;
    char* wB = wA + ABYTES;

    // tile boundary: writes visible + reads done (lgkm drain); vmcnt NOT
    // drained -> next tile's global loads stay in flight across the barrier.
    LGKM0();
    __builtin_amdgcn_s_barrier();
    SBAR0();

    if (t + 1 < NTIL) LOADS((t + 1) * BK);  // consumed after 3 MFMA phases
    SBAR0();

    // A fragments for all 3 phases (read once, 32 VGPR)
    bf16x8 aF[4][2];
#pragma unroll
    for (int mi = 0; mi < 4; ++mi)
#pragma unroll
      for (int s = 0; s < 2; ++s)
        aF[mi][s] = *(const bf16x8*)lds_addr(
            rA, wrow + mi * 16 + (lane & 15), s * 32 + (lane >> 4) * 8);

    // 3 phases: each reads one B n-pair, then a 16-MFMA cluster
#pragma unroll
    for (int p = 0; p < 3; ++p) {
      bf16x8 bF[2][2];
#pragma unroll
      for (int ni = 0; ni < 2; ++ni)
#pragma unroll
        for (int s = 0; s < 2; ++s)
          bF[ni][s] = *(const bf16x8*)lds_addr(
              rB, wcol + (2 * p + ni) * 16 + (lane & 15),
              s * 32 + (lane >> 4) * 8);
      LGKM0();
      __builtin_amdgcn_s_setprio(1);
#pragma unroll
      for (int s = 0; s < 2; ++s)
#pragma unroll
        for (int mi = 0; mi < 4; ++mi)
#pragma unroll
          for (int ni = 0; ni < 2; ++ni)
            acc[mi][2 * p + ni] = __builtin_amdgcn_mfma_f32_16x16x32_bf16(
                aF[mi][s], bF[ni][s], acc[mi][2 * p + ni], 0, 0, 0);
      __builtin_amdgcn_s_setprio(0);
      SBAR0();
    }

    // cvt+write next tile (reg-dep vmcnt wait; loads are ~3 phases old)
    if (t + 1 < NTIL) STORE(wA, wB);
  }

  // ---- epilogue: atomic accumulate (24 blocks collide: 12L x 2K) ----
  // C/D layout (m89-verified): col = lane&15, row = (lane>>4)*4 + j
  const int orow = brow + wrow + ((lane >> 4) << 2);
  const int ocol = ncol + wcol + (lane & 15);
#pragma unroll
  for (int mi = 0; mi < 4; ++mi)
#pragma unroll
    for (int ni = 0; ni < 6; ++ni)
#pragma unroll
      for (int j = 0; j < 4; ++j)
        atomicAdd(out + (size_t)(orow + mi * 16 + j) * ND + (ocol + ni * 16),
                  acc[mi][ni][j]);
}

extern "C" void kernel_launch(void* const* d_in, const int* in_sizes, int n_in,
                              void* d_out, int out_size, void* d_ws, size_t ws_size,
                              hipStream_t stream) {
  const float* acts = (const float*)d_in[0];
  const float* W    = (const float*)d_in[1];
  const float* bias = (const float*)d_in[2];
  const int*   lidx = (const int*)d_in[3];
  float* out = (float*)d_out;

  const int L = in_sizes[0] / (NB * NF);               // 12
  const int nwg = (ND / BN) * (NB / BM) * SPLITK * L;  // 768 = 3 x 256 CUs

  hipFuncSetAttribute((const void*)gemm_kernel,
                      hipFuncAttributeMaxDynamicSharedMemorySize, 2 * BUFBYTES);

  bias_init_kernel<<<dim3((NB * ND + 255) / 256), 256, 0, stream>>>(bias, lidx, out);
  gemm_kernel<<<dim3(nwg), 512, 2 * BUFBYTES, stream>>>(acts, W, lidx, out, nwg);
}